// Round 1
// baseline (418.951 us; speedup 1.0000x reference)
//
#include <hip/hip_runtime.h>

// MaskedLoss: out = sum_b sum_{(i,j) in unique(rows,cols)} (yt[b,i,j]-yp[b,i,j])^2
// B=64, N=1000, K=128. Only <=128 mask positions matter; gather instead of
// streaming the 2x256MB tensors.

#define MB 64
#define MN 1000
#define MK 128
#define NTHREADS 256

__global__ __launch_bounds__(NTHREADS) void masked_loss_kernel(
    const float* __restrict__ yt, const float* __restrict__ yp,
    const int* __restrict__ rows, const int* __restrict__ cols,
    float* __restrict__ out)
{
    __shared__ int   s_idx[MK];
    __shared__ int   s_dup[MK];
    __shared__ float s_part[NTHREADS / 64];

    const int t = threadIdx.x;

    // 1) linear index per mask entry
    if (t < MK) {
        s_idx[t] = rows[t] * MN + cols[t];
    }
    __syncthreads();

    // 2) dedupe: keep first occurrence only (set-to-1 semantics)
    if (t < MK) {
        const int my = s_idx[t];
        int dup = 0;
        for (int k = 0; k < t; ++k) {
            if (s_idx[k] == my) { dup = 1; break; }
        }
        s_dup[t] = dup;
    }
    __syncthreads();

    // 3) gather + square-accumulate over B*K work items
    float sum = 0.0f;
    const long long NN = (long long)MN * MN;
    for (int w = t; w < MB * MK; w += NTHREADS) {
        const int k = w & (MK - 1);
        const int b = w >> 7;  // w / MK
        if (!s_dup[k]) {
            const long long off = (long long)b * NN + (long long)s_idx[k];
            const float d = yt[off] - yp[off];
            sum += d * d;
        }
    }

    // 4) wave64 shuffle reduce, then LDS across the 4 waves
    #pragma unroll
    for (int o = 32; o > 0; o >>= 1) sum += __shfl_down(sum, o, 64);
    const int wave = t >> 6;
    const int lane = t & 63;
    if (lane == 0) s_part[wave] = sum;
    __syncthreads();
    if (t == 0) {
        out[0] = s_part[0] + s_part[1] + s_part[2] + s_part[3];
    }
}

extern "C" void kernel_launch(void* const* d_in, const int* in_sizes, int n_in,
                              void* d_out, int out_size, void* d_ws, size_t ws_size,
                              hipStream_t stream) {
    const float* yt   = (const float*)d_in[0];
    const float* yp   = (const float*)d_in[1];
    const int*   rows = (const int*)d_in[2];
    const int*   cols = (const int*)d_in[3];
    float* out = (float*)d_out;

    masked_loss_kernel<<<1, NTHREADS, 0, stream>>>(yt, yp, rows, cols, out);
}

// Round 2
// 386.402 us; speedup vs baseline: 1.0842x; 1.0842x over previous
//
#include <hip/hip_runtime.h>

// MaskedLoss: out = sum_b sum_{(i,j) in unique(rows,cols)} (yt[b,i,j]-yp[b,i,j])^2
// B=64, N=1000, K=128. Only <=128 mask positions matter; gather instead of
// streaming the 2x256MB tensors.
//
// R2: one block per batch (64 blocks x 128 threads), one (yt,yp) pair per
// thread, unconditional loads for max memory-level parallelism across CUs.
// Dedupe (set-to-1 semantics) recomputed per block in LDS. Partials combined
// with one fp32 atomicAdd per block; out[0] zeroed by a 1-thread init kernel.

#define MB 64
#define MN 1000
#define MK 128

__global__ void init_out(float* __restrict__ out) {
    out[0] = 0.0f;
}

__global__ __launch_bounds__(MK) void masked_loss_kernel(
    const float* __restrict__ yt, const float* __restrict__ yp,
    const int* __restrict__ rows, const int* __restrict__ cols,
    float* __restrict__ out)
{
    __shared__ int   s_idx[MK];
    __shared__ float s_part[2];

    const int t = threadIdx.x;   // 0..127 : mask-entry index
    const int b = blockIdx.x;    // 0..63  : batch index

    // 1) linear index per mask entry
    const int my = rows[t] * MN + cols[t];
    s_idx[t] = my;
    __syncthreads();

    // 2) dedupe: entry counts iff no earlier entry has the same index
    int keep = 1;
    for (int k = 0; k < t; ++k) {
        if (s_idx[k] == my) { keep = 0; break; }
    }

    // 3) unconditional gather (address always valid), zero out duplicates
    const long long off = (long long)b * (MN * MN) + (long long)my;
    const float d = yt[off] - yp[off];
    float sum = keep ? d * d : 0.0f;

    // 4) wave64 shuffle reduce across 2 waves, one atomic per block
    #pragma unroll
    for (int o = 32; o > 0; o >>= 1) sum += __shfl_down(sum, o, 64);
    const int wave = t >> 6;
    if ((t & 63) == 0) s_part[wave] = sum;
    __syncthreads();
    if (t == 0) {
        atomicAdd(out, s_part[0] + s_part[1]);
    }
}

extern "C" void kernel_launch(void* const* d_in, const int* in_sizes, int n_in,
                              void* d_out, int out_size, void* d_ws, size_t ws_size,
                              hipStream_t stream) {
    const float* yt   = (const float*)d_in[0];
    const float* yp   = (const float*)d_in[1];
    const int*   rows = (const int*)d_in[2];
    const int*   cols = (const int*)d_in[3];
    float* out = (float*)d_out;

    init_out<<<1, 1, 0, stream>>>(out);
    masked_loss_kernel<<<MB, MK, 0, stream>>>(yt, yp, rows, cols, out);
}

// Round 3
// 382.473 us; speedup vs baseline: 1.0954x; 1.0103x over previous
//
#include <hip/hip_runtime.h>

// MaskedLoss: out = sum_b sum_{(i,j) in unique(rows,cols)} (yt[b,i,j]-yp[b,i,j])^2
// B=64, N=1000, K=128. Only <=128 mask positions matter; gather instead of
// streaming the 2x256MB tensors.
//
// R3: - init kernel replaced by 4-byte hipMemsetAsync (one fewer dispatch)
//     - dedupe scan is break-free + unrolled (pipelined LDS reads, ~0.3us,
//       instead of a latency-bound dependent chain with early exit)
//     - gather loads issued right after the barrier, BEFORE the dedupe scan,
//       so ~900cy HBM latency hides under the scan (loads can't go before
//       __syncthreads: compiler drains vmcnt(0) at s_barrier)

#define MB 64
#define MN 1000
#define MK 128

__global__ __launch_bounds__(MK) void masked_loss_kernel(
    const float* __restrict__ yt, const float* __restrict__ yp,
    const int* __restrict__ rows, const int* __restrict__ cols,
    float* __restrict__ out)
{
    __shared__ int   s_idx[MK];
    __shared__ float s_part[2];

    const int t = threadIdx.x;   // 0..127 : mask-entry index
    const int b = blockIdx.x;    // 0..63  : batch index

    const int my = rows[t] * MN + cols[t];
    s_idx[t] = my;
    __syncthreads();

    // Issue the scattered gather loads first; dedupe scan below overlaps
    // with their HBM latency.
    const size_t off = (size_t)b * (size_t)(MN * MN) + (size_t)my;
    const float vt = yt[off];
    const float vp = yp[off];

    // Dedupe (set-to-1 semantics): entry counts iff no earlier equal index.
    // Break-free so the 127 LDS reads pipeline at throughput, not latency.
    int keep = 1;
    #pragma unroll 16
    for (int k = 0; k < MK; ++k) {
        keep &= (int)((k >= t) | (s_idx[k] != my));
    }

    const float d = vt - vp;
    float sum = keep ? d * d : 0.0f;

    // wave64 shuffle reduce across 2 waves, one atomic per block
    #pragma unroll
    for (int o = 32; o > 0; o >>= 1) sum += __shfl_down(sum, o, 64);
    const int wave = t >> 6;
    if ((t & 63) == 0) s_part[wave] = sum;
    __syncthreads();
    if (t == 0) {
        atomicAdd(out, s_part[0] + s_part[1]);
    }
}

extern "C" void kernel_launch(void* const* d_in, const int* in_sizes, int n_in,
                              void* d_out, int out_size, void* d_ws, size_t ws_size,
                              hipStream_t stream) {
    const float* yt   = (const float*)d_in[0];
    const float* yp   = (const float*)d_in[1];
    const int*   rows = (const int*)d_in[2];
    const int*   cols = (const int*)d_in[3];
    float* out = (float*)d_out;

    hipMemsetAsync(out, 0, sizeof(float), stream);
    masked_loss_kernel<<<MB, MK, 0, stream>>>(yt, yp, rows, cols, out);
}